// Round 1
// baseline (147.162 us; speedup 1.0000x reference)
//
#include <hip/hip_runtime.h>
#include <hip/hip_bf16.h>

// ---------------------------------------------------------------------------
// AttentionLayer (DIN-style): per-token MLP(256->80->40->1) + masked softmax.
// Math restructure: din@W1 = t@U + [s | t*s] @ [V;X]  (U=W1a+W1c, V=W1b-W1c,
// X=W1d), t@U folded into a per-batch bias. Layers 1-2 on bf16 MFMA
// (16x16x32, f32 accum), layer 3 + softmax in f32.
// Block = 1 batch, 4 waves; each wave owns 16-row tiles independently
// (no block barrier in the hot section). Per-wave 4KB LDS slot: A' then H1
// in place, XOR-swizzled ((row&7)<<4 on byte offset) against 256B-stride
// bank conflicts.
// ---------------------------------------------------------------------------

#define WS_WCT   0            // bf16 [80][128]  WcT[c][k] = [V;X][k][c]
#define WS_W2T   20480        // bf16 [48][96]   W2T[c][k] (zero-padded)
#define WS_U     29696        // f32  [64][80]   U[d][h]
#define WS_B2P   50176        // f32  [48]       b2 zero-padded
#define WS_W3P   50368        // f32  [48]       W3 zero-padded

typedef __attribute__((ext_vector_type(8))) short short8;
typedef __attribute__((ext_vector_type(4))) float f32x4;

static __device__ __forceinline__ unsigned short f2bf(float f) {
    unsigned int u = __builtin_bit_cast(unsigned int, f);
    u = (u + 0x7FFFu + ((u >> 16) & 1u)) >> 16;   // RNE, finite inputs
    return (unsigned short)u;
}

#define FENCE() do { asm volatile("s_waitcnt lgkmcnt(0)" ::: "memory"); \
                     __builtin_amdgcn_sched_barrier(0); } while (0)

// ---------------- weight prep: one tiny block, runs before main ------------
__global__ __launch_bounds__(256) void prep_kernel(
    const float* __restrict__ W1, const float* __restrict__ b1,
    const float* __restrict__ W2, const float* __restrict__ b2,
    const float* __restrict__ W3, unsigned char* __restrict__ ws)
{
    const int tid = threadIdx.x;
    unsigned short* wcT = (unsigned short*)(ws + WS_WCT);
    for (int idx = tid; idx < 80 * 128; idx += 256) {
        int c = idx >> 7, k = idx & 127;
        float v;
        if (k < 64) v = W1[(64 + k) * 80 + c] - W1[(128 + k) * 80 + c]; // V
        else        v = W1[(192 + (k - 64)) * 80 + c];                  // X
        wcT[idx] = f2bf(v);
    }
    unsigned short* w2T = (unsigned short*)(ws + WS_W2T);
    for (int idx = tid; idx < 48 * 96; idx += 256) {
        int c = idx / 96, k = idx % 96;
        float v = (c < 40 && k < 80) ? W2[k * 40 + c] : 0.0f;
        w2T[idx] = f2bf(v);
    }
    float* Uf = (float*)(ws + WS_U);
    for (int idx = tid; idx < 64 * 80; idx += 256) {
        int d = idx / 80, h = idx % 80;
        Uf[idx] = W1[d * 80 + h] + W1[(128 + d) * 80 + h];
    }
    float* b2p = (float*)(ws + WS_B2P);
    float* w3p = (float*)(ws + WS_W3P);
    for (int idx = tid; idx < 48; idx += 256) {
        b2p[idx] = (idx < 40) ? b2[idx] : 0.0f;
        w3p[idx] = (idx < 40) ? W3[idx] : 0.0f;
    }
}

// ---------------- main kernel: one block per batch --------------------------
__global__ __launch_bounds__(256, 2) void attn_kernel(
    const float* __restrict__ seq, const float* __restrict__ tgt,
    const int* __restrict__ mask, const float* __restrict__ b1,
    const unsigned char* __restrict__ ws, float* __restrict__ out)
{
    __shared__ __align__(16) unsigned char slots[4][4096]; // per-wave A'/H1
    __shared__ float bias1[80];
    __shared__ float scores[208];
    __shared__ float red[8];

    const int tid = threadIdx.x;
    const int b   = blockIdx.x;
    const int l   = tid & 63;
    const int w   = tid >> 6;
    const int cb  = l & 15;        // tile col (B,D) / tile row (A)
    const int kq  = l >> 4;        // k-quarter
    const int kbB = kq * 8;        // bf16 k base
    const int kbA = kq * 16;       // byte k base for A-frag reads

    // ---- B fragments in registers (from ws; identical for every block) ----
    const unsigned short* wcT = (const unsigned short*)(ws + WS_WCT);
    short8 bL1[4][5];
    #pragma unroll
    for (int kt = 0; kt < 4; ++kt)
        #pragma unroll
        for (int nt = 0; nt < 5; ++nt)
            bL1[kt][nt] = *(const short8*)(wcT + (cb + 16 * nt) * 128 + kt * 32 + kbB);
    const unsigned short* w2T = (const unsigned short*)(ws + WS_W2T);
    short8 bL2[3][3];
    #pragma unroll
    for (int kt = 0; kt < 3; ++kt)
        #pragma unroll
        for (int nt = 0; nt < 3; ++nt)
            bL2[kt][nt] = *(const short8*)(w2T + (cb + 16 * nt) * 96 + kt * 32 + kbB);
    const float* b2p = (const float*)(ws + WS_B2P);
    const float* w3p = (const float*)(ws + WS_W3P);
    float b2r[3], w3r[3];
    #pragma unroll
    for (int nt = 0; nt < 3; ++nt) { b2r[nt] = b2p[cb + 16 * nt]; w3r[nt] = w3p[cb + 16 * nt]; }

    // ---- bias1 = b1 + t @ U (f32, exact) ----
    if (tid < 80) {
        const float* Uf = (const float*)(ws + WS_U);
        const float* t  = tgt + b * 64;
        float acc = b1[tid];
        for (int d = 0; d < 64; ++d) acc += t[d] * Uf[d * 80 + tid];
        bias1[tid] = acc;
    }
    __syncthreads();

    float biasc[5];
    #pragma unroll
    for (int nt = 0; nt < 5; ++nt) biasc[nt] = bias1[nt * 16 + cb];

    unsigned char* slot = slots[w];
    const int c0 = cb * 4;                       // f32 col base for staging
    const float4 t4 = *(const float4*)(tgt + b * 64 + c0);

    for (int rt = w; rt < 13; rt += 4) {
        // ---- stage A'[16][128] bf16 = [s | t*s], swizzled ----
        #pragma unroll
        for (int p = 0; p < 4; ++p) {
            int rr = p * 4 + kq;
            int grow = rt * 16 + rr; grow = grow > 199 ? 199 : grow;
            float4 s4 = *(const float4*)(seq + (size_t)b * 12800 + (size_t)grow * 64 + c0);
            uint2 lov, hiv;
            lov.x = (unsigned)f2bf(s4.x) | ((unsigned)f2bf(s4.y) << 16);
            lov.y = (unsigned)f2bf(s4.z) | ((unsigned)f2bf(s4.w) << 16);
            hiv.x = (unsigned)f2bf(t4.x * s4.x) | ((unsigned)f2bf(t4.y * s4.y) << 16);
            hiv.y = (unsigned)f2bf(t4.z * s4.z) | ((unsigned)f2bf(t4.w * s4.w) << 16);
            int sw = (rr & 7) << 4;
            *(uint2*)(slot + rr * 256 + ((c0 * 2) ^ sw))       = lov;
            *(uint2*)(slot + rr * 256 + ((128 + c0 * 2) ^ sw)) = hiv;
        }
        FENCE();

        // ---- layer 1: (16x128)@(128x80), 20 MFMA ----
        f32x4 acc[5] = {};
        const int swi = (cb & 7) << 4;
        #pragma unroll
        for (int kt = 0; kt < 4; ++kt) {
            short8 af = *(const short8*)(slot + cb * 256 + ((kt * 64 + kbA) ^ swi));
            #pragma unroll
            for (int nt = 0; nt < 5; ++nt)
                acc[nt] = __builtin_amdgcn_mfma_f32_16x16x32_bf16(af, bL1[kt][nt], acc[nt], 0, 0, 0);
        }
        FENCE();

        // ---- bias+relu -> H1 bf16, same slot (cols 80..95 stale => W2T rows zero) ----
        #pragma unroll
        for (int nt = 0; nt < 5; ++nt) {
            #pragma unroll
            for (int j = 0; j < 4; ++j) {
                float h = acc[nt][j] + biasc[nt];
                h = fmaxf(h, 0.0f);
                int r = kq * 4 + j, c = nt * 16 + cb;
                *(unsigned short*)(slot + r * 256 + ((c * 2) ^ ((r & 7) << 4))) = f2bf(h);
            }
        }
        FENCE();

        // ---- layer 2: (16x96)@(96x48), 9 MFMA ----
        f32x4 acc2[3] = {};
        #pragma unroll
        for (int kt = 0; kt < 3; ++kt) {
            short8 a2 = *(const short8*)(slot + cb * 256 + ((kt * 64 + kbA) ^ swi));
            #pragma unroll
            for (int nt = 0; nt < 3; ++nt)
                acc2[nt] = __builtin_amdgcn_mfma_f32_16x16x32_bf16(a2, bL2[kt][nt], acc2[nt], 0, 0, 0);
        }

        // ---- layer 3 (f32) + 16-lane reduce ----
        float pj[4];
        #pragma unroll
        for (int j = 0; j < 4; ++j) {
            float p = 0.0f;
            #pragma unroll
            for (int nt = 0; nt < 3; ++nt) {
                float h2 = acc2[nt][j] + b2r[nt];
                h2 = fmaxf(h2, 0.0f);
                p += h2 * w3r[nt];
            }
            pj[j] = p;
        }
        #pragma unroll
        for (int st = 1; st < 16; st <<= 1) {
            #pragma unroll
            for (int j = 0; j < 4; ++j) pj[j] += __shfl_xor(pj[j], st, 64);
        }
        if (cb == 0) {
            #pragma unroll
            for (int j = 0; j < 4; ++j) scores[rt * 16 + kq * 4 + j] = pj[j];
        }
        FENCE();
    }
    __syncthreads();

    // ---- masked softmax over S=200 (f32) ----
    float v = -3.0e38f;
    if (tid < 200) {
        int m = mask[b * 200 + tid];
        v = m ? scores[tid] : -1.0e9f;
    }
    float mx = v;
    #pragma unroll
    for (int st = 32; st >= 1; st >>= 1) mx = fmaxf(mx, __shfl_xor(mx, st, 64));
    if (l == 0) red[w] = mx;
    __syncthreads();
    float bmax = fmaxf(fmaxf(red[0], red[1]), fmaxf(red[2], red[3]));
    float e = (tid < 200) ? expf(v - bmax) : 0.0f;
    float sm = e;
    #pragma unroll
    for (int st = 32; st >= 1; st >>= 1) sm += __shfl_xor(sm, st, 64);
    if (l == 0) red[4 + w] = sm;
    __syncthreads();
    float bsum = red[4] + red[5] + red[6] + red[7];
    if (tid < 200) out[b * 200 + tid] = e / bsum;
}

extern "C" void kernel_launch(void* const* d_in, const int* in_sizes, int n_in,
                              void* d_out, int out_size, void* d_ws, size_t ws_size,
                              hipStream_t stream)
{
    const float* seq = (const float*)d_in[0];
    const float* tgt = (const float*)d_in[1];
    const int*   msk = (const int*)d_in[2];
    const float* W1  = (const float*)d_in[3];
    const float* b1  = (const float*)d_in[4];
    const float* W2  = (const float*)d_in[5];
    const float* b2  = (const float*)d_in[6];
    const float* W3  = (const float*)d_in[7];
    // d_in[8] = b3: cancels in softmax (uniform shift on unmasked lanes).
    unsigned char* ws = (unsigned char*)d_ws;
    float* out = (float*)d_out;

    prep_kernel<<<1, 256, 0, stream>>>(W1, b1, W2, b2, W3, ws);
    attn_kernel<<<4096, 256, 0, stream>>>(seq, tgt, msk, b1, ws, out);
}

// Round 3
// 78.329 us; speedup vs baseline: 1.8788x; 1.8788x over previous
//
#include <hip/hip_runtime.h>
#include <hip/hip_bf16.h>

// ---------------------------------------------------------------------------
// AttentionLayer: per-token MLP(256->80->40->1) + masked softmax.
// din@W1 = t@U + [s | t*s] @ [V;X]; bias = b1 + t@U computed per wave in
// registers (U staged in LDS). Streaming score kernel: 512 blocks x 4
// independent waves, 26 row-tiles each (exactly 2 batches/wave), 1-tile
// register prefetch, A-frags built directly in registers, W1 pre-swizzled in
// LDS, layer-2 operand-swapped (reduce = 2 shfl). Raw scores -> d_out;
// softmax kernel finishes in place.
// ws footprint = 50560 B exactly (round-1-proven size). H1 slots zero-inited.
// ---------------------------------------------------------------------------

#define WS_WCT   0        // bf16 [80][128] PRE-SWIZZLED: u16 idx = c*128 + (k ^ ((c&7)<<3))
#define WS_W2T   20480    // bf16 [48][96]  W2T[c2][k], zero-padded (c2>=40 or k>=80)
#define WS_B2P   29696    // f32  [48]
#define WS_W3P   29888    // f32  [48]
#define WS_U     30080    // f32  [64][80]  U[d][h] = W1a+W1c   (ends at 50560)

typedef __attribute__((ext_vector_type(8))) short short8;
typedef __attribute__((ext_vector_type(4))) float f32x4;

static __device__ __forceinline__ unsigned short f2bf(float f) {
    unsigned int u = __builtin_bit_cast(unsigned int, f);
    u = (u + 0x7FFFu + ((u >> 16) & 1u)) >> 16;   // RNE, finite inputs
    return (unsigned short)u;
}

static __device__ __forceinline__ short8 pk8(float4 a, float4 b) {
    short8 r;
    r[0] = (short)f2bf(a.x); r[1] = (short)f2bf(a.y);
    r[2] = (short)f2bf(a.z); r[3] = (short)f2bf(a.w);
    r[4] = (short)f2bf(b.x); r[5] = (short)f2bf(b.y);
    r[6] = (short)f2bf(b.z); r[7] = (short)f2bf(b.w);
    return r;
}

#define FENCE() do { asm volatile("s_waitcnt lgkmcnt(0)" ::: "memory"); \
                     __builtin_amdgcn_sched_barrier(0); } while (0)

// ---------------- weight prep (1 block) ------------------------------------
__global__ __launch_bounds__(256) void prep_w_kernel(
    const float* __restrict__ W1, const float* __restrict__ W2,
    const float* __restrict__ b2, const float* __restrict__ W3,
    unsigned char* __restrict__ ws)
{
    const int tid = threadIdx.x;
    unsigned short* wcT = (unsigned short*)(ws + WS_WCT);
    for (int idx = tid; idx < 80 * 128; idx += 256) {
        int c = idx >> 7, k = idx & 127;
        float v;
        if (k < 64) v = W1[(64 + k) * 80 + c] - W1[(128 + k) * 80 + c]; // V
        else        v = W1[(192 + (k - 64)) * 80 + c];                  // X
        wcT[(c << 7) + (k ^ ((c & 7) << 3))] = f2bf(v);                 // swizzled
    }
    unsigned short* w2T = (unsigned short*)(ws + WS_W2T);
    for (int idx = tid; idx < 48 * 96; idx += 256) {
        int c = idx / 96, k = idx % 96;
        float v = (c < 40 && k < 80) ? W2[k * 40 + c] : 0.0f;
        w2T[idx] = f2bf(v);
    }
    float* b2p = (float*)(ws + WS_B2P);
    float* w3p = (float*)(ws + WS_W3P);
    for (int idx = tid; idx < 48; idx += 256) {
        b2p[idx] = (idx < 40) ? b2[idx] : 0.0f;
        w3p[idx] = (idx < 40) ? W3[idx] : 0.0f;
    }
    float* Uf = (float*)(ws + WS_U);
    for (int idx = tid; idx < 64 * 80; idx += 256) {
        int d = idx / 80, h = idx - d * 80;
        Uf[idx] = W1[d * 80 + h] + W1[(128 + d) * 80 + h];
    }
}

// ---------------- streaming score kernel ------------------------------------
__global__ __launch_bounds__(256, 2) void score_kernel(
    const float* __restrict__ seq, const float* __restrict__ tgt,
    const float* __restrict__ b1g, const unsigned char* __restrict__ ws,
    float* __restrict__ out)
{
    __shared__ __align__(16) unsigned char w1s[20480];      // pre-swizzled W1
    __shared__ __align__(16) float Us[5120];                // U[d][h]
    __shared__ __align__(16) unsigned char slots[4][4096];  // per-wave H1

    const int tid = threadIdx.x;
    {   // stage W1 + U (linear copies, pre-formatted in ws), zero H1 slots
        const float4* s1 = (const float4*)(ws + WS_WCT);
        float4* d1 = (float4*)w1s;
        const float4* s2 = (const float4*)(ws + WS_U);
        float4* d2 = (float4*)Us;
        #pragma unroll
        for (int i = 0; i < 5; ++i) {
            d1[tid + 256 * i] = s1[tid + 256 * i];
            d2[tid + 256 * i] = s2[tid + 256 * i];
        }
        float4 z = {0.f, 0.f, 0.f, 0.f};
        float4* sz = (float4*)slots;
        #pragma unroll
        for (int i = 0; i < 4; ++i) sz[tid + 256 * i] = z;
    }
    __syncthreads();

    const int l  = tid & 63;
    const int w  = tid >> 6;
    const int cb = l & 15;
    const int kq = l >> 4;
    const int swi = (cb & 7) << 4;

    // W2^T A-fragments + per-lane bias/w3 (c2 = mt*16 + kq*4 + j)
    const unsigned short* w2T = (const unsigned short*)(ws + WS_W2T);
    short8 bL2[3][3];
    #pragma unroll
    for (int kt = 0; kt < 3; ++kt)
        #pragma unroll
        for (int mt = 0; mt < 3; ++mt)
            bL2[kt][mt] = *(const short8*)(w2T + (cb + 16 * mt) * 96 + kt * 32 + kq * 8);
    const float* b2p = (const float*)(ws + WS_B2P);
    const float* w3p = (const float*)(ws + WS_W3P);
    float bw[3][4], wv[3][4];
    #pragma unroll
    for (int mt = 0; mt < 3; ++mt)
        #pragma unroll
        for (int j = 0; j < 4; ++j) {
            int c2 = mt * 16 + kq * 4 + j;
            bw[mt][j] = b2p[c2]; wv[mt][j] = w3p[c2];
        }

    unsigned char* slot = slots[w];
    const int gw = blockIdx.x * 4 + w;            // 0..2047
    const int bA = gw * 2;                        // this wave's 2 batches
    int tau = gw * 26;                            // 26 tiles = 2 full batches

    // per-wave bias registers: bias[c] = b1[c] + t@U[:,c], f32 (channels nt*16+cb)
    float biasA[5], biasB[5];
    #pragma unroll
    for (int nt = 0; nt < 5; ++nt) {
        float v0 = b1g[nt * 16 + cb];
        biasA[nt] = v0; biasB[nt] = v0;
    }
    for (int d = 0; d < 64; ++d) {
        float tA = tgt[bA * 64 + d];
        float tB = tgt[bA * 64 + 64 + d];
        #pragma unroll
        for (int nt = 0; nt < 5; ++nt) {
            float u = Us[d * 80 + nt * 16 + cb];
            biasA[nt] += tA * u; biasB[nt] += tB * u;
        }
    }

#define STAGE(TAU, S0,S1,S2,S3, T0,T1,T2,T3) do {                              \
        int tc = (TAU); tc = tc > 53247 ? 53247 : tc;                          \
        int b_ = tc / 13; int tt_ = tc - b_ * 13;                              \
        int row = tt_ * 16 + cb; row = row > 199 ? 199 : row;                  \
        const float* sp = seq + ((size_t)b_ * 200 + row) * 64 + kq * 8;        \
        S0 = *(const float4*)sp;        S1 = *(const float4*)(sp + 4);         \
        S2 = *(const float4*)(sp + 32); S3 = *(const float4*)(sp + 36);        \
        const float* tp = tgt + (size_t)b_ * 64 + kq * 8;                      \
        T0 = *(const float4*)tp;        T1 = *(const float4*)(tp + 4);         \
        T2 = *(const float4*)(tp + 32); T3 = *(const float4*)(tp + 36);        \
    } while (0)

#define PROCESS(TAU, S0,S1,S2,S3, T0,T1,T2,T3) do {                            \
        int b_ = (TAU) / 13; int tt_ = (TAU) - b_ * 13;                        \
        float biasc_[5];                                                       \
        _Pragma("unroll")                                                      \
        for (int nt = 0; nt < 5; ++nt)                                         \
            biasc_[nt] = (b_ == bA) ? biasA[nt] : biasB[nt];                   \
        short8 a0 = pk8(S0, S1), a1 = pk8(S2, S3);                             \
        short8 a2 = pk8(T0 * S0, T1 * S1), a3 = pk8(T2 * S2, T3 * S3);         \
        f32x4 acc[5] = {};                                                     \
        _Pragma("unroll")                                                      \
        for (int kt = 0; kt < 4; ++kt) {                                       \
            short8 av = kt == 0 ? a0 : kt == 1 ? a1 : kt == 2 ? a2 : a3;       \
            _Pragma("unroll")                                                  \
            for (int nt = 0; nt < 5; ++nt) {                                   \
                short8 bf = *(const short8*)(w1s + (cb + 16 * nt) * 256 +      \
                                             ((kt * 64 + kq * 16) ^ swi));     \
                acc[nt] = __builtin_amdgcn_mfma_f32_16x16x32_bf16(av, bf, acc[nt], 0, 0, 0); \
            }                                                                  \
        }                                                                      \
        _Pragma("unroll")                                                      \
        for (int nt = 0; nt < 5; ++nt)                                         \
            _Pragma("unroll")                                                  \
            for (int j = 0; j < 4; ++j) {                                      \
                float h = fmaxf(acc[nt][j] + biasc_[nt], 0.0f);                \
                int r = kq * 4 + j, c = nt * 16 + cb;                          \
                *(unsigned short*)(slot + r * 256 + ((2 * c) ^ ((r & 7) << 4))) = f2bf(h); \
            }                                                                  \
        FENCE();                                                               \
        f32x4 acc2[3] = {};                                                    \
        _Pragma("unroll")                                                      \
        for (int kt = 0; kt < 3; ++kt) {                                       \
            short8 hf = *(const short8*)(slot + cb * 256 +                     \
                                         ((kt * 64 + kq * 16) ^ swi));         \
            _Pragma("unroll")                                                  \
            for (int mt = 0; mt < 3; ++mt)                                     \
                acc2[mt] = __builtin_amdgcn_mfma_f32_16x16x32_bf16(bL2[kt][mt], hf, acc2[mt], 0, 0, 0); \
        }                                                                      \
        float part = 0.0f;                                                     \
        _Pragma("unroll")                                                      \
        for (int mt = 0; mt < 3; ++mt)                                         \
            _Pragma("unroll")                                                  \
            for (int j = 0; j < 4; ++j)                                        \
                part += fmaxf(acc2[mt][j] + bw[mt][j], 0.0f) * wv[mt][j];      \
        part += __shfl_xor(part, 16, 64);                                      \
        part += __shfl_xor(part, 32, 64);                                      \
        if (l < 16) {                                                          \
            int row = tt_ * 16 + cb;                                           \
            if (row < 200) out[(size_t)b_ * 200 + row] = part;                 \
        }                                                                      \
    } while (0)

    float4 sa0, sa1, sa2, sa3, ta0, ta1, ta2, ta3;
    float4 sb0, sb1, sb2, sb3, tb0, tb1, tb2, tb3;
    STAGE(tau, sa0, sa1, sa2, sa3, ta0, ta1, ta2, ta3);
    for (int i = 0; i < 13; ++i) {
        STAGE(tau + 1, sb0, sb1, sb2, sb3, tb0, tb1, tb2, tb3);
        PROCESS(tau,    sa0, sa1, sa2, sa3, ta0, ta1, ta2, ta3);
        STAGE(tau + 2, sa0, sa1, sa2, sa3, ta0, ta1, ta2, ta3);
        PROCESS(tau + 1, sb0, sb1, sb2, sb3, tb0, tb1, tb2, tb3);
        tau += 2;
    }
}

// ---------------- masked softmax, in place on d_out -------------------------
__global__ __launch_bounds__(256) void softmax_kernel(
    const int* __restrict__ mask, float* __restrict__ out)
{
    const int l = threadIdx.x & 63;
    const int w = threadIdx.x >> 6;
    const int b = blockIdx.x * 4 + w;             // grid 1024 -> 4096 batches
    float* po = out + (size_t)b * 200;
    const int* pm = mask + (size_t)b * 200;
    float v[4];
    #pragma unroll
    for (int j = 0; j < 4; ++j) {
        int tk = l + 64 * j;
        v[j] = (tk < 200) ? (pm[tk] ? po[tk] : -1.0e9f) : -3.0e38f;
    }
    float mx = fmaxf(fmaxf(v[0], v[1]), fmaxf(v[2], v[3]));
    #pragma unroll
    for (int st = 32; st >= 1; st >>= 1) mx = fmaxf(mx, __shfl_xor(mx, st, 64));
    float e[4], sm = 0.0f;
    #pragma unroll
    for (int j = 0; j < 4; ++j) {
        int tk = l + 64 * j;
        e[j] = (tk < 200) ? expf(v[j] - mx) : 0.0f;
        sm += e[j];
    }
    #pragma unroll
    for (int st = 32; st >= 1; st >>= 1) sm += __shfl_xor(sm, st, 64);
    float inv = 1.0f / sm;
    #pragma unroll
    for (int j = 0; j < 4; ++j) {
        int tk = l + 64 * j;
        if (tk < 200) po[tk] = e[j] * inv;
    }
}

extern "C" void kernel_launch(void* const* d_in, const int* in_sizes, int n_in,
                              void* d_out, int out_size, void* d_ws, size_t ws_size,
                              hipStream_t stream)
{
    const float* seq = (const float*)d_in[0];
    const float* tgt = (const float*)d_in[1];
    const int*   msk = (const int*)d_in[2];
    const float* W1  = (const float*)d_in[3];
    const float* b1  = (const float*)d_in[4];
    const float* W2  = (const float*)d_in[5];
    const float* b2  = (const float*)d_in[6];
    const float* W3  = (const float*)d_in[7];
    // d_in[8] = b3: uniform shift, cancels in softmax.
    unsigned char* ws = (unsigned char*)d_ws;
    float* out = (float*)d_out;

    prep_w_kernel<<<1, 256, 0, stream>>>(W1, W2, b2, W3, ws);
    score_kernel<<<512, 256, 0, stream>>>(seq, tgt, b1, ws, out);
    softmax_kernel<<<1024, 256, 0, stream>>>(msk, out);
}